// Round 4
// baseline (282.377 us; speedup 1.0000x reference)
//
#include <hip/hip_runtime.h>
#include <hip/hip_bf16.h>
#include <math.h>
#include <float.h>

// Problem constants (x: [8192,128] f32, n_images=2)
static constexpr int NN    = 8192;
static constexpr int DD    = 128;
static constexpr int PP    = 4096;              // persons
static constexpr int TILE  = 128;
static constexpr int TT    = NN / TILE;         // 64 tiles per dim
static constexpr int NBLK  = TT * (TT + 1) / 2; // 2080 upper-tri tile pairs
static constexpr int NC    = NBLK * 2;          // 2 candidates per tile block
static constexpr int GRP   = 1088;              // 8 rows x 128B (fp8) + 64B pad
static constexpr int PLDS  = 16 * GRP;          // 17408 B per 128x128 fp8 panel
static constexpr int GEMMB = NBLK / 4;          // 520 pipelined blocks, 4 tiles each
static constexpr int SSB   = 64;                // sim_self blocks folded into k_top2
static constexpr int SMEM  = 4 * PLDS + 64;     // A0,B0,A1,B1 + reduce scratch

struct Cand { float v; unsigned idx; };

using f32x4 = __attribute__((ext_vector_type(4))) float;

typedef const __attribute__((address_space(1))) unsigned int* gas_uint;
typedef __attribute__((address_space(3))) unsigned int* las_uint;

// async 16B/lane global->LDS DMA. LDS dest = wave-uniform base + lane*16.
// Global address may vary per lane. [m03/m97/m104]
__device__ __forceinline__ void dma16(const void* g, const void* l) {
    __builtin_amdgcn_global_load_lds(
        (gas_uint)(unsigned long long)g,
        (las_uint)(unsigned)(unsigned long long)l, 16, 0, 0);
}

__device__ __forceinline__ void push1(float& v1, unsigned& i1, float& v2, unsigned& i2,
                                      float w, unsigned j) {
    if (w > v1) { v2 = v1; i2 = i1; v1 = w; i1 = j; }
    else if (w > v2) { v2 = w; i2 = j; }
}

__device__ __forceinline__ void merge2(float& v1, unsigned& i1, float& v2, unsigned& i2,
                                       float w1, unsigned j1, float w2, unsigned j2) {
    if (w1 > v1) {
        float nv2; unsigned ni2;
        if (v1 >= w2) { nv2 = v1; ni2 = i1; } else { nv2 = w2; ni2 = j2; }
        v1 = w1; i1 = j1; v2 = nv2; i2 = ni2;
    } else if (w1 > v2) {
        v2 = w1; i2 = j1;
    }
}

// ---- kernel 0: x -> fp8 e4m3 copy (1MB), conversion only ----
__global__ __launch_bounds__(256) void k_prep(const float* __restrict__ x,
                                              unsigned char* __restrict__ xb) {
    const int tid = threadIdx.x;
    int chunk = blockIdx.x * 256 + tid;          // 65536 chunks x 16 floats
    const float4* s = (const float4*)(x + (size_t)chunk * 16);
    float4 f0 = s[0], f1 = s[1], f2 = s[2], f3 = s[3];
    unsigned w0 = 0, w1 = 0, w2 = 0, w3 = 0;
    w0 = __builtin_amdgcn_cvt_pk_fp8_f32(f0.x, f0.y, w0, false);
    w0 = __builtin_amdgcn_cvt_pk_fp8_f32(f0.z, f0.w, w0, true);
    w1 = __builtin_amdgcn_cvt_pk_fp8_f32(f1.x, f1.y, w1, false);
    w1 = __builtin_amdgcn_cvt_pk_fp8_f32(f1.z, f1.w, w1, true);
    w2 = __builtin_amdgcn_cvt_pk_fp8_f32(f2.x, f2.y, w2, false);
    w2 = __builtin_amdgcn_cvt_pk_fp8_f32(f2.z, f2.w, w2, true);
    w3 = __builtin_amdgcn_cvt_pk_fp8_f32(f3.x, f3.y, w3, false);
    w3 = __builtin_amdgcn_cvt_pk_fp8_f32(f3.z, f3.w, w3, true);
    uint4 o = {w0, w1, w2, w3};
    *(uint4*)(xb + (size_t)chunk * 16) = o;
}

// ---- kernel 1: fp8 MFMA top-2, pipelined 4 tiles per block (T3+T4).
// Per tile: issue STAGE(t+1) -> counted s_waitcnt vmcnt(8) (next tile's DMAs
// stay in flight across the barrier) -> raw s_barrier -> MFMA + epilogue ->
// barrier. DMA stream never drains in steady state; cold latency paid once
// per 4 tiles. Blocks >= GEMMB compute sim_self (reads x only). ----
__global__ __launch_bounds__(256, 2) void k_top2(const unsigned char* __restrict__ xb,
                                                 const float* __restrict__ x,
                                                 double* __restrict__ ss,
                                                 Cand* __restrict__ cands) {
    extern __shared__ __align__(16) char smem[];

    const int tid  = threadIdx.x;
    const int wv   = tid >> 6;      // wave 0..3
    const int lane = tid & 63;
    const int bid  = blockIdx.x;

    if (bid >= GEMMB) {
        // ---- sim_self[p] = dot(x[p], x[p+1]) in double, wave per person ----
        int b = bid - GEMMB;               // 0..63
        #pragma unroll 4
        for (int u = 0; u < 16; ++u) {
            int p = b * 64 + wv * 16 + u;  // 0..4095
            const float* a  = x + (size_t)p * DD;
            const float* bb = a + DD;
            double s = (double)a[lane] * (double)bb[lane]
                     + (double)a[lane + 64] * (double)bb[lane + 64];
            #pragma unroll
            for (int off = 32; off >= 1; off >>= 1) s += __shfl_down(s, off);
            if (lane == 0) ss[p] = s;
        }
        return;
    }

    char* bufA[2] = { smem,            smem + 2 * PLDS };
    char* bufB[2] = { smem + PLDS,     smem + 3 * PLDS };
    float*    sv1 = (float*)(smem + 4 * PLDS);
    float*    sv2 = sv1 + 4;
    unsigned* si1 = (unsigned*)(sv2 + 4);
    unsigned* si2 = si1 + 4;

    // decode the 4 consecutive tiles (ti<=tj) this block owns
    int tis[4], tjs[4];
    {
        int rem = bid * 4, ti = 0;
        while (rem >= TT - ti) { rem -= (TT - ti); ++ti; }
        #pragma unroll
        for (int t = 0; t < 4; ++t) {
            tis[t] = ti; tjs[t] = ti + rem;
            if (++rem >= TT - ti) { rem = 0; ++ti; }
        }
    }

    const int grow = lane >> 3;                      // DMA: row in group 0..7
    const int colb = ((lane & 7) * 16) ^ (grow << 4);// swizzled 16B chunk

    const int wm   = wv >> 1;       // wave row 0..1 (64 rows)
    const int wn   = wv & 1;        // wave col 0..1 (64 cols)
    const int quad = lane >> 4;     // 0..3
    const int r16  = lane & 15;     // 0..15
    const int rl   = r16 & 7;       // row within group
    const int rh   = r16 >> 3;      // group parity within 16-row fragment
    const int xs   = rl << 4;       // XOR term matching the staging swizzle

    // prologue: stage tile 0 into buffer 0 (8 dma16 per wave)
    #pragma unroll
    for (int q = 0; q < 4; ++q) {
        int g = wv * 4 + q;
        dma16(xb + (size_t)(tis[0] * TILE + g * 8 + grow) * DD + colb, bufA[0] + g * GRP);
        dma16(xb + (size_t)(tjs[0] * TILE + g * 8 + grow) * DD + colb, bufB[0] + g * GRP);
    }

    #pragma unroll
    for (int t = 0; t < 4; ++t) {
        char* A = bufA[t & 1];
        char* B = bufB[t & 1];

        // issue next tile's stage into the other buffer (freed by barrier at
        // end of iteration t-1); its 8 DMAs remain in flight through compute(t)
        if (t < 3) {
            char* An = bufA[(t + 1) & 1];
            char* Bn = bufB[(t + 1) & 1];
            #pragma unroll
            for (int q = 0; q < 4; ++q) {
                int g = wv * 4 + q;
                dma16(xb + (size_t)(tis[t + 1] * TILE + g * 8 + grow) * DD + colb,
                      An + g * GRP);
                dma16(xb + (size_t)(tjs[t + 1] * TILE + g * 8 + grow) * DD + colb,
                      Bn + g * GRP);
            }
            asm volatile("s_waitcnt vmcnt(8)" ::: "memory");  // tile t landed
        } else {
            asm volatile("s_waitcnt vmcnt(0)" ::: "memory");
        }
        __builtin_amdgcn_sched_barrier(0);
        __builtin_amdgcn_s_barrier();   // all waves' tile-t DMAs visible

        // ---- compute tile t ----
        const char* Abase = A + (wm * 8 + rh) * GRP + rl * 128 + (quad & 1) * 8;
        const char* Bbase = B + (wn * 8 + rh) * GRP + rl * 128 + (quad & 1) * 8;

        f32x4 acc[4][4];
        #pragma unroll
        for (int mi = 0; mi < 4; ++mi)
            #pragma unroll
            for (int nj = 0; nj < 4; ++nj)
                acc[mi][nj] = (f32x4){0.f, 0.f, 0.f, 0.f};

        #pragma unroll
        for (int kc = 0; kc < 4; ++kc) {        // 4 chunks of K=32
            const int co = (kc * 32 + (quad >> 1) * 16) ^ xs;
            long af[4], bq[4];
            #pragma unroll
            for (int mi = 0; mi < 4; ++mi) {
                af[mi] = *(const long*)(Abase + mi * (2 * GRP) + co);
                bq[mi] = *(const long*)(Bbase + mi * (2 * GRP) + co);
            }
            __builtin_amdgcn_s_setprio(1);
            #pragma unroll
            for (int mi = 0; mi < 4; ++mi)
                #pragma unroll
                for (int nj = 0; nj < 4; ++nj)
                    acc[mi][nj] = __builtin_amdgcn_mfma_f32_16x16x32_fp8_fp8(
                        af[mi], bq[nj], acc[mi][nj], 0, 0, 0);
            __builtin_amdgcn_s_setprio(0);
        }

        // ---- epilogue: per-lane top-2 over valid (i<j) ----
        // C/D layout: col = lane&15, row = (lane>>4)*4 + reg
        const int ibase = tis[t] * TILE + wm * 64;
        const int jbase = tjs[t] * TILE + wn * 64;
        float v1 = -INFINITY, v2 = -INFINITY;
        unsigned i1 = 0, i2 = 0;
        #pragma unroll
        for (int mi = 0; mi < 4; ++mi) {
            #pragma unroll
            for (int nj = 0; nj < 4; ++nj) {
                int gj = jbase + nj * 16 + r16;
                #pragma unroll
                for (int reg = 0; reg < 4; ++reg) {
                    int gi = ibase + mi * 16 + quad * 4 + reg;
                    if (gi < gj) {
                        unsigned idx = (unsigned)(gi * NN + gj);
                        push1(v1, i1, v2, i2, acc[mi][nj][reg], idx);
                    }
                }
            }
        }
        #pragma unroll
        for (int off = 32; off >= 1; off >>= 1) {
            float    w1 = __shfl_down(v1, off);
            unsigned j1 = (unsigned)__shfl_down((int)i1, off);
            float    w2 = __shfl_down(v2, off);
            unsigned j2 = (unsigned)__shfl_down((int)i2, off);
            merge2(v1, i1, v2, i2, w1, j1, w2, j2);
        }
        if (lane == 0) { sv1[wv] = v1; si1[wv] = i1; sv2[wv] = v2; si2[wv] = i2; }
        // raw barrier (NOT __syncthreads: that would drain vmcnt and kill the
        // in-flight next-tile DMAs). lgkmcnt(0) makes the ds_writes visible.
        asm volatile("s_waitcnt lgkmcnt(0)" ::: "memory");
        __builtin_amdgcn_s_barrier();
        if (tid == 0) {
            for (int w = 1; w < 4; ++w)
                merge2(v1, i1, v2, i2, sv1[w], si1[w], sv2[w], si2[w]);
            int tau = bid * 4 + t;
            cands[tau * 2]     = {v1, i1};
            cands[tau * 2 + 1] = {v2, i2};
        }
        // separate tile t's scratch reads / buffer use from tile t+1's writes
        __builtin_amdgcn_s_barrier();
    }
}

// ---- kernel 2: approx top-2 -> exact recheck (double) -> final mean ----
// Margin 10.0 covers fp8 approximation error; final value computed from exact
// f64 dots, so output is independent of the fp8 approximation.
__global__ __launch_bounds__(1024) void k_final(const float* __restrict__ x,
                                                const double* __restrict__ ss,
                                                const Cand* __restrict__ cands,
                                                float* __restrict__ out) {
    __shared__ float redv[32];          // 16 waves x 2
    __shared__ float s_thresh;
    __shared__ int cnt;
    __shared__ unsigned qidx[256];
    __shared__ double qex[256];
    __shared__ double sd1, sd2;
    __shared__ unsigned stopi;
    __shared__ double sacc[1024];

    const int tid  = threadIdx.x;
    const int wv   = tid >> 6;          // 0..15
    const int lane = tid & 63;
    if (tid == 0) cnt = 0;

    // Phase A: approx global top-2 VALUES
    float v1 = -INFINITY, v2 = -INFINITY;
    for (int e = tid; e < NC; e += 1024) {
        float v = cands[e].v;
        if (v > v1) { v2 = v1; v1 = v; }
        else if (v > v2) v2 = v;
    }
    #pragma unroll
    for (int off = 32; off >= 1; off >>= 1) {
        float w1 = __shfl_down(v1, off);
        float w2 = __shfl_down(v2, off);
        if (w1 > v1) { v2 = (v1 >= w2) ? v1 : w2; v1 = w1; }
        else if (w1 > v2) v2 = w1;
    }
    if (lane == 0) { redv[wv * 2] = v1; redv[wv * 2 + 1] = v2; }
    __syncthreads();
    if (tid == 0) {
        float a1 = -INFINITY, a2 = -INFINITY;
        for (int e = 0; e < 32; ++e) {
            float v = redv[e];
            if (v > a1) { a2 = a1; a1 = v; }
            else if (v > a2) a2 = v;
        }
        s_thresh = a2 - 10.0f;   // margin >> fp8 dot-product error bound
    }
    __syncthreads();
    const float thresh = s_thresh;

    // Phase B: gather all candidates within margin of approx top-2
    for (int e = tid; e < NC; e += 1024) {
        if (cands[e].v >= thresh) {
            int k = atomicAdd(&cnt, 1);
            if (k < 256) qidx[k] = cands[e].idx;
        }
    }
    __syncthreads();
    const int n = cnt < 256 ? cnt : 256;

    // Phase C: exact double dot for each qualifying candidate (one wave each)
    for (int c = wv; c < n; c += 16) {
        unsigned idx = qidx[c];
        unsigned gi = idx >> 13;       // / 8192
        unsigned gj = idx & 8191;
        const float* pa = x + (size_t)gi * DD;
        const float* pb = x + (size_t)gj * DD;
        double s = (double)pa[lane] * (double)pb[lane]
                 + (double)pa[lane + 64] * (double)pb[lane + 64];
        #pragma unroll
        for (int off = 32; off >= 1; off >>= 1) s += __shfl_down(s, off);
        if (lane == 0) qex[c] = s;
    }
    __syncthreads();

    // Phase D: exact top-2 over rechecked candidates
    if (tid == 0) {
        double d1 = -DBL_MAX, d2 = -DBL_MAX;
        unsigned bi = 0;
        for (int c = 0; c < n; ++c) {
            double v = qex[c];
            if (v > d1) { d2 = d1; d1 = v; bi = qidx[c]; }
            else if (v > d2) d2 = v;
        }
        sd1 = d1; sd2 = d2; stopi = bi;
    }
    __syncthreads();

    const double top1 = sd1, top2 = sd2;
    const unsigned topi = stopi;

    // Phase E: mean(sim_oth / sim_self)
    double acc = 0.0;
    for (int p = tid; p < PP; p += 1024) {
        unsigned selfidx = (unsigned)(p * NN + p + 1);
        double so = (topi == selfidx) ? top2 : top1;
        acc += so / ss[p];
    }
    sacc[tid] = acc;
    __syncthreads();
    for (int s = 512; s >= 1; s >>= 1) {
        if (tid < s) sacc[tid] += sacc[tid + s];
        __syncthreads();
    }
    if (tid == 0) out[0] = (float)(sacc[0] / (double)PP);
}

extern "C" void kernel_launch(void* const* d_in, const int* in_sizes, int n_in,
                              void* d_out, int out_size, void* d_ws, size_t ws_size,
                              hipStream_t stream) {
    (void)in_sizes; (void)n_in; (void)out_size; (void)ws_size;
    const float* x = (const float*)d_in[0];
    float* out = (float*)d_out;

    double* ss  = (double*)d_ws;                                  // 32 KB
    Cand* cands = (Cand*)((char*)d_ws + PP * sizeof(double));     // ~33 KB
    unsigned char* xb = (unsigned char*)((char*)d_ws + 131072);   // 1 MB fp8 copy

    hipFuncSetAttribute((const void*)k_top2,
                        hipFuncAttributeMaxDynamicSharedMemorySize, SMEM);

    k_prep<<<256, 256, 0, stream>>>(x, xb);
    k_top2<<<GEMMB + SSB, 256, SMEM, stream>>>(xb, x, ss, cands);
    k_final<<<1, 1024, 0, stream>>>(x, ss, cands, out);
}

// Round 5
// 205.179 us; speedup vs baseline: 1.3762x; 1.3762x over previous
//
#include <hip/hip_runtime.h>
#include <hip/hip_bf16.h>
#include <math.h>
#include <float.h>

// Problem constants (x: [8192,128] f32, n_images=2)
static constexpr int NN    = 8192;
static constexpr int DD    = 128;
static constexpr int PP    = 4096;              // persons
static constexpr int TILE  = 128;
static constexpr int TT    = NN / TILE;         // 64 tiles per dim
static constexpr int NBLK  = TT * (TT + 1) / 2; // 2080 upper-tri tile pairs
static constexpr int GBLK  = NBLK / 2;          // 1040 blocks x 2 tiles each
static constexpr int NC    = NBLK * 2;          // 2 candidates per tile
static constexpr int GRP   = 1088;              // 8 rows x 128B (fp8) + 64B pad
static constexpr int PLDS  = 16 * GRP;          // 17408 B per 128x128 fp8 panel

struct Cand { float v; unsigned idx; };

using f32x4 = __attribute__((ext_vector_type(4))) float;

typedef const __attribute__((address_space(1))) unsigned int* gas_uint;
typedef __attribute__((address_space(3))) unsigned int* las_uint;

// async 16B/lane global->LDS DMA. LDS dest = wave-uniform base + lane*16.
// Global address may vary per lane. [m03/m97/m104]
__device__ __forceinline__ void dma16(const void* g, const void* l) {
    __builtin_amdgcn_global_load_lds(
        (gas_uint)(unsigned long long)g,
        (las_uint)(unsigned)(unsigned long long)l, 16, 0, 0);
}

__device__ __forceinline__ void push1(float& v1, unsigned& i1, float& v2, unsigned& i2,
                                      float w, unsigned j) {
    if (w > v1) { v2 = v1; i2 = i1; v1 = w; i1 = j; }
    else if (w > v2) { v2 = w; i2 = j; }
}

__device__ __forceinline__ void merge2(float& v1, unsigned& i1, float& v2, unsigned& i2,
                                       float w1, unsigned j1, float w2, unsigned j2) {
    if (w1 > v1) {
        float nv2; unsigned ni2;
        if (v1 >= w2) { nv2 = v1; ni2 = i1; } else { nv2 = w2; ni2 = j2; }
        v1 = w1; i1 = j1; v2 = nv2; i2 = ni2;
    } else if (w1 > v2) {
        v2 = w1; i2 = j1;
    }
}

__device__ __forceinline__ void dmerge2(double& v1, unsigned& i1, double& v2,
                                        double w1, unsigned j1, double w2) {
    if (w1 > v1) {
        double nv2 = (v1 >= w2) ? v1 : w2;
        v2 = nv2; v1 = w1; i1 = j1;
    } else if (w1 > v2) {
        v2 = w1;
    }
}

// ---- kernel 0: x -> fp8 e4m3 copy (1MB) + sim_self (double) + S_inv reset ----
__global__ __launch_bounds__(256) void k_prep(const float* __restrict__ x,
                                              unsigned char* __restrict__ xb,
                                              double* __restrict__ ss,
                                              double* __restrict__ S_inv) {
    const int tid = threadIdx.x;
    if (blockIdx.x < 256) {
        // 65536 chunks x 16 floats -> 16 fp8 (16B out per thread)
        int chunk = blockIdx.x * 256 + tid;
        const float4* s = (const float4*)(x + (size_t)chunk * 16);
        float4 f0 = s[0], f1 = s[1], f2 = s[2], f3 = s[3];
        unsigned w0 = 0, w1 = 0, w2 = 0, w3 = 0;
        w0 = __builtin_amdgcn_cvt_pk_fp8_f32(f0.x, f0.y, w0, false);
        w0 = __builtin_amdgcn_cvt_pk_fp8_f32(f0.z, f0.w, w0, true);
        w1 = __builtin_amdgcn_cvt_pk_fp8_f32(f1.x, f1.y, w1, false);
        w1 = __builtin_amdgcn_cvt_pk_fp8_f32(f1.z, f1.w, w1, true);
        w2 = __builtin_amdgcn_cvt_pk_fp8_f32(f2.x, f2.y, w2, false);
        w2 = __builtin_amdgcn_cvt_pk_fp8_f32(f2.z, f2.w, w2, true);
        w3 = __builtin_amdgcn_cvt_pk_fp8_f32(f3.x, f3.y, w3, false);
        w3 = __builtin_amdgcn_cvt_pk_fp8_f32(f3.z, f3.w, w3, true);
        uint4 o = {w0, w1, w2, w3};
        *(uint4*)(xb + (size_t)chunk * 16) = o;
    } else {
        // 64 blocks: sim_self[p] = dot(x[p], x[p+1]) in double, wave per person
        if (blockIdx.x == 256 && tid == 0) *S_inv = 0.0;   // graph-replay reset
        int b = blockIdx.x - 256;          // 0..63
        const int wv = tid >> 6, lane = tid & 63;
        #pragma unroll 4
        for (int u = 0; u < 16; ++u) {
            int p = b * 64 + wv * 16 + u;  // 0..4095
            const float* a  = x + (size_t)p * DD;
            const float* bb = a + DD;
            double s = (double)a[lane] * (double)bb[lane]
                     + (double)a[lane + 64] * (double)bb[lane + 64];
            #pragma unroll
            for (int off = 32; off >= 1; off >>= 1) s += __shfl_down(s, off);
            if (lane == 0) ss[p] = s;
        }
    }
}

// ---- kernel 1: fp8 MFMA top-2, 1040 blocks x 2 sequential tiles.
// Body per tile identical to the verified R3 single-phase structure (stage
// full K=128, one __syncthreads, MFMA, epilogue). Halved block count doubles
// per-block lifetime -> CP launch ramp (~21 WG/us) covers the 4-block/CU
// residency cap for a larger fraction of the kernel. Block GBLK reduces
// S_inv = sum(1/ss). ----
__global__ __launch_bounds__(256, 4) void k_top2(const unsigned char* __restrict__ xb,
                                                 const double* __restrict__ ss,
                                                 double* __restrict__ S_inv,
                                                 Cand* __restrict__ cands) {
    __shared__ __align__(16) char As[PLDS];
    __shared__ __align__(16) char Bs[PLDS];
    __shared__ float sv1[4], sv2[4];
    __shared__ unsigned si1[4], si2[4];

    const int tid  = threadIdx.x;
    const int wv   = tid >> 6;      // wave 0..3
    const int lane = tid & 63;
    const int bid  = blockIdx.x;

    if (bid == GBLK) {
        // ---- S_inv = sum_p 1/ss[p] (ss from k_prep) ----
        double a = 0.0;
        #pragma unroll
        for (int u = 0; u < 16; ++u) a += 1.0 / ss[u * 256 + tid];
        #pragma unroll
        for (int off = 32; off >= 1; off >>= 1) a += __shfl_down(a, off);
        if (lane == 0) atomicAdd(S_inv, a);
        return;
    }

    const int grow = lane >> 3;                       // DMA: row in group 0..7
    const int colb = ((lane & 7) * 16) ^ (grow << 4); // swizzled 16B chunk

    const int wm   = wv >> 1;       // wave row 0..1 (64 rows)
    const int wn   = wv & 1;        // wave col 0..1 (64 cols)
    const int quad = lane >> 4;     // 0..3
    const int r16  = lane & 15;     // 0..15
    const int rl   = r16 & 7;       // row within group
    const int rh   = r16 >> 3;      // group parity within 16-row fragment
    const int xs   = rl << 4;       // XOR term matching the staging swizzle

    for (int it = 0; it < 2; ++it) {
        const int tau = bid + it * GBLK;      // tile-pair index 0..2079
        int rem = tau, ti = 0;
        while (rem >= TT - ti) { rem -= (TT - ti); ++ti; }
        const int tj = ti + rem;

        // ---- stage both 128x128 fp8 panels, single phase, 8 dma16/wave ----
        #pragma unroll
        for (int t = 0; t < 4; ++t) {
            int g = wv * 4 + t;                     // group 0..15
            dma16(xb + (size_t)(ti * TILE + g * 8 + grow) * DD + colb, As + g * GRP);
            dma16(xb + (size_t)(tj * TILE + g * 8 + grow) * DD + colb, Bs + g * GRP);
        }
        __syncthreads();   // vmcnt(0) drain + barrier: DMA landed, prev reads done

        const char* Abase = As + (wm * 8 + rh) * GRP + rl * 128 + (quad & 1) * 8;
        const char* Bbase = Bs + (wn * 8 + rh) * GRP + rl * 128 + (quad & 1) * 8;

        f32x4 acc[4][4];
        #pragma unroll
        for (int mi = 0; mi < 4; ++mi)
            #pragma unroll
            for (int nj = 0; nj < 4; ++nj)
                acc[mi][nj] = (f32x4){0.f, 0.f, 0.f, 0.f};

        #pragma unroll
        for (int kc = 0; kc < 4; ++kc) {        // 4 chunks of K=32
            const int co = (kc * 32 + (quad >> 1) * 16) ^ xs;
            long af[4], bq[4];
            #pragma unroll
            for (int mi = 0; mi < 4; ++mi) {
                af[mi] = *(const long*)(Abase + mi * (2 * GRP) + co);
                bq[mi] = *(const long*)(Bbase + mi * (2 * GRP) + co);
            }
            #pragma unroll
            for (int mi = 0; mi < 4; ++mi)
                #pragma unroll
                for (int nj = 0; nj < 4; ++nj)
                    acc[mi][nj] = __builtin_amdgcn_mfma_f32_16x16x32_fp8_fp8(
                        af[mi], bq[nj], acc[mi][nj], 0, 0, 0);
        }

        // ---- epilogue: per-lane top-2 over valid (i<j) ----
        // C/D layout: col = lane&15, row = (lane>>4)*4 + reg (dtype-independent)
        const int ibase = ti * TILE + wm * 64;
        const int jbase = tj * TILE + wn * 64;
        float v1 = -INFINITY, v2 = -INFINITY;
        unsigned i1 = 0, i2 = 0;
        #pragma unroll
        for (int mi = 0; mi < 4; ++mi) {
            #pragma unroll
            for (int nj = 0; nj < 4; ++nj) {
                int gj = jbase + nj * 16 + r16;
                #pragma unroll
                for (int reg = 0; reg < 4; ++reg) {
                    int gi = ibase + mi * 16 + quad * 4 + reg;
                    if (gi < gj) {
                        unsigned idx = (unsigned)(gi * NN + gj);
                        push1(v1, i1, v2, i2, acc[mi][nj][reg], idx);
                    }
                }
            }
        }
        #pragma unroll
        for (int off = 32; off >= 1; off >>= 1) {
            float    w1 = __shfl_down(v1, off);
            unsigned j1 = (unsigned)__shfl_down((int)i1, off);
            float    w2 = __shfl_down(v2, off);
            unsigned j2 = (unsigned)__shfl_down((int)i2, off);
            merge2(v1, i1, v2, i2, w1, j1, w2, j2);
        }
        if (lane == 0) { sv1[wv] = v1; si1[wv] = i1; sv2[wv] = v2; si2[wv] = i2; }
        __syncthreads();
        if (tid == 0) {
            for (int w = 1; w < 4; ++w)
                merge2(v1, i1, v2, i2, sv1[w], si1[w], sv2[w], si2[w]);
            cands[tau * 2]     = {v1, i1};
            cands[tau * 2 + 1] = {v2, i2};
        }
        // next iteration's __syncthreads (after staging) protects As/Bs/sv reuse
    }
}

// ---- kernel 2: approx top-2 -> exact recheck (double) -> O(1) final ----
// Margin 10.0 covers fp8 approximation error; final value computed from exact
// f64 dots. mean = (top1*S_inv - [topi self]*(top1-top2)/ss[gi]) / PP.
__global__ __launch_bounds__(1024) void k_final(const float* __restrict__ x,
                                                const double* __restrict__ ss,
                                                const double* __restrict__ S_inv,
                                                const Cand* __restrict__ cands,
                                                float* __restrict__ out) {
    __shared__ float redv[32];          // 16 waves x 2
    __shared__ float s_thresh;
    __shared__ int cnt;
    __shared__ unsigned qidx[256];
    __shared__ double qex[256];
    __shared__ double wdv1[16], wdv2[16];
    __shared__ unsigned wdi[16];

    const int tid  = threadIdx.x;
    const int wv   = tid >> 6;          // 0..15
    const int lane = tid & 63;
    if (tid == 0) cnt = 0;

    // Phase A: approx global top-2 VALUES
    float v1 = -INFINITY, v2 = -INFINITY;
    for (int e = tid; e < NC; e += 1024) {
        float v = cands[e].v;
        if (v > v1) { v2 = v1; v1 = v; }
        else if (v > v2) v2 = v;
    }
    #pragma unroll
    for (int off = 32; off >= 1; off >>= 1) {
        float w1 = __shfl_down(v1, off);
        float w2 = __shfl_down(v2, off);
        if (w1 > v1) { v2 = (v1 >= w2) ? v1 : w2; v1 = w1; }
        else if (w1 > v2) v2 = w1;
    }
    if (lane == 0) { redv[wv * 2] = v1; redv[wv * 2 + 1] = v2; }
    __syncthreads();
    if (tid == 0) {
        float a1 = -INFINITY, a2 = -INFINITY;
        for (int e = 0; e < 32; ++e) {
            float v = redv[e];
            if (v > a1) { a2 = a1; a1 = v; }
            else if (v > a2) a2 = v;
        }
        s_thresh = a2 - 10.0f;   // margin >> fp8 dot-product error bound
    }
    __syncthreads();
    const float thresh = s_thresh;

    // Phase B: gather all candidates within margin of approx top-2
    for (int e = tid; e < NC; e += 1024) {
        if (cands[e].v >= thresh) {
            int k = atomicAdd(&cnt, 1);
            if (k < 256) qidx[k] = cands[e].idx;
        }
    }
    __syncthreads();
    const int n = cnt < 256 ? cnt : 256;

    // Phase C: exact double dot for each qualifying candidate (one wave each)
    for (int c = wv; c < n; c += 16) {
        unsigned idx = qidx[c];
        unsigned gi = idx >> 13;       // / 8192
        unsigned gj = idx & 8191;
        const float* pa = x + (size_t)gi * DD;
        const float* pb = x + (size_t)gj * DD;
        double s = (double)pa[lane] * (double)pb[lane]
                 + (double)pa[lane + 64] * (double)pb[lane + 64];
        #pragma unroll
        for (int off = 32; off >= 1; off >>= 1) s += __shfl_down(s, off);
        if (lane == 0) qex[c] = s;
    }
    __syncthreads();

    // Phase D: exact top-2 over rechecked candidates, parallel across threads
    double d1 = -DBL_MAX, d2 = -DBL_MAX;
    unsigned bi = 0;
    if (tid < n) { d1 = qex[tid]; bi = qidx[tid]; }
    #pragma unroll
    for (int off = 32; off >= 1; off >>= 1) {
        double w1   = __shfl_down(d1, off);
        unsigned j1 = (unsigned)__shfl_down((int)bi, off);
        double w2   = __shfl_down(d2, off);
        dmerge2(d1, bi, d2, w1, j1, w2);
    }
    if (lane == 0) { wdv1[wv] = d1; wdv2[wv] = d2; wdi[wv] = bi; }
    __syncthreads();

    // Phase E: O(1) final mean using precomputed S_inv
    if (tid == 0) {
        for (int w = 1; w < 16; ++w)
            dmerge2(d1, bi, d2, wdv1[w], wdi[w], wdv2[w]);
        unsigned gi = bi >> 13, gj = bi & 8191;
        double corr = 0.0;
        if (gj == gi + 1 && gi < (unsigned)PP)      // top1 is person gi's self pair
            corr = (d1 - d2) / ss[gi];
        out[0] = (float)((d1 * (*S_inv) - corr) / (double)PP);
    }
}

extern "C" void kernel_launch(void* const* d_in, const int* in_sizes, int n_in,
                              void* d_out, int out_size, void* d_ws, size_t ws_size,
                              hipStream_t stream) {
    (void)in_sizes; (void)n_in; (void)out_size; (void)ws_size;
    const float* x = (const float*)d_in[0];
    float* out = (float*)d_out;

    double* ss    = (double*)d_ws;                                // 32 KB
    Cand*  cands  = (Cand*)((char*)d_ws + PP * sizeof(double));   // ~33 KB
    double* S_inv = (double*)((char*)d_ws + 81920);               // 8 B
    unsigned char* xb = (unsigned char*)((char*)d_ws + 131072);   // 1 MB fp8 copy

    k_prep<<<320, 256, 0, stream>>>(x, xb, ss, S_inv);
    k_top2<<<GBLK + 1, 256, 0, stream>>>(xb, ss, S_inv, cands);
    k_final<<<1, 1024, 0, stream>>>(x, ss, S_inv, cands, out);
}